// Round 5
// baseline (744.029 us; speedup 1.0000x reference)
//
#include <hip/hip_runtime.h>

// BERT-CRF NLL, fused: one block per batch computes feats = X[b] @ W^T + b
// into LDS, then CRF forward recursion + gold score in-block. Second kernel
// does the batch mean.
//
// R5: phase-1 restructure for latency hiding. R4 was latency-bound
// (VGPR_Count=108 < the 128+ needed for acc[8][12]+8 inflight float4 ->
// compiler serialized loads; 8 waves/CU). Now 512 threads/block, 32 groups
// x 4 rows (acc[4][12]=48 regs), explicit double-buffered X loads,
// __launch_bounds__(512,4) -> 16 waves/CU, VGPR<=128.

#define Bsz 512
#define Tt  128
#define Hh  768
#define Ll  12
#define START_TAG 9
#define NEGV -10000.0f

__global__ __launch_bounds__(512, 4) void fused_kernel(
    const float* __restrict__ X, const float* __restrict__ W,
    const float* __restrict__ bias, const float* __restrict__ trans,
    const int* __restrict__ labels, float* __restrict__ bscores)
{
  __shared__ float sW[Ll * Hh];    // 36 KB
  __shared__ float sT[Ll * Ll];
  __shared__ float sB[Ll];
  __shared__ float sF[Tt * Ll];    // 6 KB feats
  __shared__ float sFwd, sGold;

  const int tid = threadIdx.x;
  const int b   = blockIdx.x;

  for (int i = tid; i < Ll * Hh / 4; i += 512)
    reinterpret_cast<float4*>(sW)[i] = reinterpret_cast<const float4*>(W)[i];
  if (tid < Ll * Ll) sT[tid] = trans[tid];
  if (tid < Ll)      sB[tid] = bias[tid];
  __syncthreads();

  // ---- phase 1: feats into sF -------------------------------------------
  const int g = tid >> 4;          // group 0..31
  const int j = tid & 15;          // lane in group
  const int row0 = g * 4;          // 4 rows per group
  const float* xb = X + ((size_t)b * Tt + row0) * Hh + 4 * j;

  float acc[4][Ll];
#pragma unroll
  for (int r = 0; r < 4; ++r)
#pragma unroll
    for (int l = 0; l < Ll; ++l) acc[r][l] = 0.f;

  float4 xv[4], nx[4];
#pragma unroll
  for (int r = 0; r < 4; ++r)
    xv[r] = *reinterpret_cast<const float4*>(xb + r * Hh);

#pragma unroll
  for (int it = 0; it < Hh / 64; ++it) {     // 12 iters; 16 lanes x f4 = 64
    if (it < Hh / 64 - 1) {
      const int hn = 64 * (it + 1);
#pragma unroll
      for (int r = 0; r < 4; ++r)
        nx[r] = *reinterpret_cast<const float4*>(xb + r * Hh + hn);
    }
    const int h = 64 * it + 4 * j;
#pragma unroll
    for (int l = 0; l < Ll; ++l) {
      const float4 wv = *reinterpret_cast<const float4*>(sW + l * Hh + h);
#pragma unroll
      for (int r = 0; r < 4; ++r)
        acc[r][l] += xv[r].x*wv.x + xv[r].y*wv.y + xv[r].z*wv.z + xv[r].w*wv.w;
    }
#pragma unroll
    for (int r = 0; r < 4; ++r) xv[r] = nx[r];
  }

#pragma unroll
  for (int r = 0; r < 4; ++r)
#pragma unroll
    for (int l = 0; l < Ll; ++l)
#pragma unroll
      for (int d = 1; d < 16; d <<= 1)
        acc[r][l] += __shfl_xor(acc[r][l], d, 16);

  if (j == 0) {
#pragma unroll
    for (int r = 0; r < 4; ++r) {
      float* o = sF + (row0 + r) * Ll;
      *reinterpret_cast<float4*>(o + 0) = make_float4(acc[r][0]+sB[0], acc[r][1]+sB[1], acc[r][2]+sB[2],  acc[r][3]+sB[3]);
      *reinterpret_cast<float4*>(o + 4) = make_float4(acc[r][4]+sB[4], acc[r][5]+sB[5], acc[r][6]+sB[6],  acc[r][7]+sB[7]);
      *reinterpret_cast<float4*>(o + 8) = make_float4(acc[r][8]+sB[8], acc[r][9]+sB[9], acc[r][10]+sB[10],acc[r][11]+sB[11]);
    }
  }
  __syncthreads();

  // ---- phase 2: CRF recursion (lanes 0-15) + gold score (wave 1) --------
  if (tid < 16) {
    const int jj = (tid < Ll) ? tid : (Ll - 1);
    float E[Ll], E0[Ll];
#pragma unroll
    for (int k = 0; k < Ll; ++k) {
      E[k]  = __expf(sT[jj * Ll + k]);
      E0[k] = __expf(sT[k]);
    }
    float beta = (tid == START_TAG) ? 0.0f : NEGV;
    float c = 0.0f;
    for (int t = 1; t < Tt; ++t) {
      const float p = __expf(beta);
      float ph[Ll];
#pragma unroll
      for (int k = 0; k < Ll; ++k) ph[k] = __shfl(p, k, 16);
      float sa = 0.f, sb = 0.f, sc = 0.f, za = 0.f, zb = 0.f, zc = 0.f;
#pragma unroll
      for (int k = 0; k < Ll; k += 3) {
        sa = fmaf(E[k],   ph[k],   sa);  za = fmaf(E0[k],   ph[k],   za);
        sb = fmaf(E[k+1], ph[k+1], sb);  zb = fmaf(E0[k+1], ph[k+1], zb);
        sc = fmaf(E[k+2], ph[k+2], sc);  zc = fmaf(E0[k+2], ph[k+2], zc);
      }
      const float s  = (sa + sb) + sc;
      const float s0 = (za + zb) + zc;
      const float a0 = __logf(s0) + sF[t * Ll];
      beta = (__logf(s) + sF[t * Ll + jj]) - a0;
      c += a0;
    }
    float bv = (tid < Ll) ? beta : NEGV;
    float m = bv;
#pragma unroll
    for (int d = 8; d >= 1; d >>= 1) m = fmaxf(m, __shfl_xor(m, d, 16));
    float p = __expf(bv - m);
#pragma unroll
    for (int d = 8; d >= 1; d >>= 1) p += __shfl_xor(p, d, 16);
    if (tid == 0) sFwd = c + m + __logf(p);
  } else if (tid >= 64 && tid < 128) {
    const int lane = tid - 64;
    const int* lab = labels + (size_t)b * Tt;
    float gs = 0.f;
    for (int t = lane; t < Tt - 1; t += 64) {
      const int pv = lab[t], nx2 = lab[t + 1];
      gs += sT[nx2 * Ll + pv] + sF[(t + 1) * Ll + nx2];
    }
#pragma unroll
    for (int d = 32; d >= 1; d >>= 1) gs += __shfl_xor(gs, d, 64);
    if (lane == 0) sGold = gs;
  }
  __syncthreads();

  if (tid == 0) bscores[b] = sFwd - sGold;
}

// ---------------------------------------------------------------- reduce
__global__ __launch_bounds__(64) void reduce_kernel(
    const float* __restrict__ bs, float* __restrict__ out)
{
  const int tid = threadIdx.x;
  float s = 0.f;
  for (int i = tid; i < Bsz; i += 64) s += bs[i];
#pragma unroll
  for (int d = 32; d >= 1; d >>= 1) s += __shfl_xor(s, d, 64);
  if (tid == 0) out[0] = s * (1.0f / Bsz);
}

// ---------------------------------------------------------------- launch
extern "C" void kernel_launch(void* const* d_in, const int* in_sizes, int n_in,
                              void* d_out, int out_size, void* d_ws, size_t ws_size,
                              hipStream_t stream) {
  const float* X     = (const float*)d_in[0];
  const float* W     = (const float*)d_in[1];
  const float* b     = (const float*)d_in[2];
  const float* trans = (const float*)d_in[3];
  const int*   lab   = (const int*)d_in[4];
  float* out = (float*)d_out;

  float* bscores = (float*)d_ws;

  fused_kernel<<<Bsz, 512, 0, stream>>>(X, W, b, trans, lab, bscores);
  reduce_kernel<<<1, 64, 0, stream>>>(bscores, out);
}